// Round 4
// baseline (284.178 us; speedup 1.0000x reference)
//
#include <hip/hip_runtime.h>

// Problem constants (from setup_inputs): B=64, L=256000
constexpr int  Bsz     = 64;
constexpr long Llen    = 256000;
constexpr int  NSEG    = 32;                 // segments per row
constexpr int  SEG_F4  = 2000;               // float4 per segment = L/4/NSEG
constexpr int  THREADS = 256;                // 4 waves
constexpr int  NBLK    = Bsz * NSEG;         // 2048 blocks = 8/CU exactly

// Fused kernel: per (b, seg) block computes 8 partial dot products
// [p0p0, p1p1, t1t1, t2t2, p0t1, p0t2, p1t1, p1t2]; the LAST block to
// finish (atomic ticket) computes the SI-SDR permutation loss.
__global__ __launch_bounds__(THREADS, 8) void pit_fused(
    const float* __restrict__ preds,   // (2, B, L) flat
    const float* __restrict__ s1,      // (B, L)
    const float* __restrict__ s2,      // (B, L)
    float* __restrict__ partials,      // (NBLK, 8)
    int* __restrict__ counter,         // zeroed each launch
    float* __restrict__ out)
{
    const int  blk  = blockIdx.x;
    const int  b    = blk >> 5;          // / NSEG
    const int  c    = blk & (NSEG - 1);  // % NSEG
    const long base = (long)b * Llen + (long)c * (SEG_F4 * 4);

    const float4* p0 = reinterpret_cast<const float4*>(preds + base);
    const float4* p1 = reinterpret_cast<const float4*>(preds + (long)Bsz * Llen + base);
    const float4* t1 = reinterpret_cast<const float4*>(s1 + base);
    const float4* t2 = reinterpret_cast<const float4*>(s2 + base);

    float a0 = 0.f, a1 = 0.f, a2 = 0.f, a3 = 0.f;
    float a4 = 0.f, a5 = 0.f, a6 = 0.f, a7 = 0.f;

    #pragma unroll 4
    for (int i = threadIdx.x; i < SEG_F4; i += THREADS) {
        const float4 x0 = p0[i];
        const float4 x1 = p1[i];
        const float4 y1 = t1[i];
        const float4 y2 = t2[i];
        a0 += x0.x*x0.x + x0.y*x0.y + x0.z*x0.z + x0.w*x0.w;
        a1 += x1.x*x1.x + x1.y*x1.y + x1.z*x1.z + x1.w*x1.w;
        a2 += y1.x*y1.x + y1.y*y1.y + y1.z*y1.z + y1.w*y1.w;
        a3 += y2.x*y2.x + y2.y*y2.y + y2.z*y2.z + y2.w*y2.w;
        a4 += x0.x*y1.x + x0.y*y1.y + x0.z*y1.z + x0.w*y1.w;
        a5 += x0.x*y2.x + x0.y*y2.y + x0.z*y2.z + x0.w*y2.w;
        a6 += x1.x*y1.x + x1.y*y1.y + x1.z*y1.z + x1.w*y1.w;
        a7 += x1.x*y2.x + x1.y*y2.y + x1.z*y2.z + x1.w*y2.w;
    }

    // Deterministic wave64 butterfly reduction on each accumulator
    #pragma unroll
    for (int m = 32; m >= 1; m >>= 1) {
        a0 += __shfl_xor(a0, m, 64);
        a1 += __shfl_xor(a1, m, 64);
        a2 += __shfl_xor(a2, m, 64);
        a3 += __shfl_xor(a3, m, 64);
        a4 += __shfl_xor(a4, m, 64);
        a5 += __shfl_xor(a5, m, 64);
        a6 += __shfl_xor(a6, m, 64);
        a7 += __shfl_xor(a7, m, 64);
    }

    __shared__ float lds[THREADS / 64][8];
    const int lane = threadIdx.x & 63;
    const int w    = threadIdx.x >> 6;
    if (lane == 0) {
        lds[w][0] = a0; lds[w][1] = a1; lds[w][2] = a2; lds[w][3] = a3;
        lds[w][4] = a4; lds[w][5] = a5; lds[w][6] = a6; lds[w][7] = a7;
    }
    __syncthreads();
    if (threadIdx.x < 8) {
        const float s = lds[0][threadIdx.x] + lds[1][threadIdx.x]
                      + lds[2][threadIdx.x] + lds[3][threadIdx.x];
        partials[(long)blk * 8 + threadIdx.x] = s;
    }

    // ---- last-block-done ticket ----
    __shared__ int is_last;
    __threadfence();                       // release: partials visible device-wide
    if (threadIdx.x == 0) {
        const int v = atomicAdd(counter, 1);
        is_last = (v == NBLK - 1);
    }
    __syncthreads();
    if (!is_last) return;
    __threadfence();                       // acquire side

    // ---- finish: lanes 0..63 = batch rows ----
    if (threadIdx.x >= 64) return;
    const int bb = threadIdx.x;

    double s0=0, s1_=0, s2_=0, s3=0, s4=0, s5=0, s6=0, s7=0;
    const float* p = partials + (long)bb * NSEG * 8;
    for (int cc = 0; cc < NSEG; ++cc) {
        s0  += (double)p[cc*8+0];
        s1_ += (double)p[cc*8+1];
        s2_ += (double)p[cc*8+2];
        s3  += (double)p[cc*8+3];
        s4  += (double)p[cc*8+4];
        s5  += (double)p[cc*8+5];
        s6  += (double)p[cc*8+6];
        s7  += (double)p[cc*8+7];
    }

    const double EPS = 1.1920928955078125e-07; // np.finfo(np.float32).eps
    const double p0p0 = s0, p1p1 = s1_, t1t1 = s2_, t2t2 = s3;
    const double p0t1 = s4, p0t2 = s5, p1t1 = s6, p1t2 = s7;

    auto sisdr = [&](double pt, double tt, double pp) -> double {
        const double alpha = (pt + EPS) / (tt + EPS);
        const double ts2   = alpha * alpha * tt;                  // ||alpha*t||^2
        const double n2    = pp - 2.0 * alpha * pt + ts2;         // ||p - alpha*t||^2
        return 10.0 * log10((ts2 + EPS) / (n2 + EPS));
    };

    const double score1 = 0.5 * (sisdr(p0t1, t1t1, p0p0) + sisdr(p1t2, t2t2, p1p1));
    const double score2 = 0.5 * (sisdr(p1t1, t1t1, p1p1) + sisdr(p0t2, t2t2, p0p0));
    double per = fmax(score1, score2);

    #pragma unroll
    for (int m = 32; m >= 1; m >>= 1) per += __shfl_xor(per, m, 64);

    if (bb == 0) out[0] = (float)(-per / (double)Bsz);
}

extern "C" void kernel_launch(void* const* d_in, const int* in_sizes, int n_in,
                              void* d_out, int out_size, void* d_ws, size_t ws_size,
                              hipStream_t stream) {
    const float* preds = (const float*)d_in[0]; // (2, B, L)
    const float* s1    = (const float*)d_in[1]; // (B, L)
    const float* s2    = (const float*)d_in[2]; // (B, L)
    float* out         = (float*)d_out;         // scalar loss
    float* partials    = (float*)d_ws;          // NBLK*8 floats = 64 KB
    int*   counter     = (int*)((char*)d_ws + (size_t)NBLK * 8 * sizeof(float));

    hipMemsetAsync(counter, 0, sizeof(int), stream); // capture-safe
    pit_fused<<<NBLK, THREADS, 0, stream>>>(preds, s1, s2, partials, counter, out);
}

// Round 5
// 48.547 us; speedup vs baseline: 5.8537x; 5.8537x over previous
//
#include <hip/hip_runtime.h>

// Problem constants (from setup_inputs): B=64, L=256000
constexpr int  Bsz     = 64;
constexpr long Llen    = 256000;
constexpr int  NSEG    = 32;                 // segments per row
constexpr int  SEG_F4  = 2000;               // float4 per segment = L/4/NSEG
constexpr int  THREADS = 256;                // 4 waves
constexpr int  NBLK    = Bsz * NSEG;         // 2048 blocks = 8/CU exactly

// Kernel 1: per (b, seg) block, compute 8 partial dot products.
// Planar output layout: partials[f * NBLK + blk], f in
// [p0p0, p1p1, t1t1, t2t2, p0t1, p0t2, p1t1, p1t2]
__global__ __launch_bounds__(THREADS) void pit_dots(
    const float* __restrict__ preds,   // (2, B, L) flat
    const float* __restrict__ s1,      // (B, L)
    const float* __restrict__ s2,      // (B, L)
    float* __restrict__ partials)      // (8, NBLK) planar
{
    const int  blk  = blockIdx.x;
    const int  b    = blk >> 5;          // / NSEG
    const int  c    = blk & (NSEG - 1);  // % NSEG
    const long base = (long)b * Llen + (long)c * (SEG_F4 * 4);

    const float4* p0 = reinterpret_cast<const float4*>(preds + base);
    const float4* p1 = reinterpret_cast<const float4*>(preds + (long)Bsz * Llen + base);
    const float4* t1 = reinterpret_cast<const float4*>(s1 + base);
    const float4* t2 = reinterpret_cast<const float4*>(s2 + base);

    float a0 = 0.f, a1 = 0.f, a2 = 0.f, a3 = 0.f;
    float a4 = 0.f, a5 = 0.f, a6 = 0.f, a7 = 0.f;

    #pragma unroll 4
    for (int i = threadIdx.x; i < SEG_F4; i += THREADS) {
        const float4 x0 = p0[i];
        const float4 x1 = p1[i];
        const float4 y1 = t1[i];
        const float4 y2 = t2[i];
        a0 += x0.x*x0.x + x0.y*x0.y + x0.z*x0.z + x0.w*x0.w;
        a1 += x1.x*x1.x + x1.y*x1.y + x1.z*x1.z + x1.w*x1.w;
        a2 += y1.x*y1.x + y1.y*y1.y + y1.z*y1.z + y1.w*y1.w;
        a3 += y2.x*y2.x + y2.y*y2.y + y2.z*y2.z + y2.w*y2.w;
        a4 += x0.x*y1.x + x0.y*y1.y + x0.z*y1.z + x0.w*y1.w;
        a5 += x0.x*y2.x + x0.y*y2.y + x0.z*y2.z + x0.w*y2.w;
        a6 += x1.x*y1.x + x1.y*y1.y + x1.z*y1.z + x1.w*y1.w;
        a7 += x1.x*y2.x + x1.y*y2.y + x1.z*y2.z + x1.w*y2.w;
    }

    // Deterministic wave64 butterfly reduction on each accumulator
    #pragma unroll
    for (int m = 32; m >= 1; m >>= 1) {
        a0 += __shfl_xor(a0, m, 64);
        a1 += __shfl_xor(a1, m, 64);
        a2 += __shfl_xor(a2, m, 64);
        a3 += __shfl_xor(a3, m, 64);
        a4 += __shfl_xor(a4, m, 64);
        a5 += __shfl_xor(a5, m, 64);
        a6 += __shfl_xor(a6, m, 64);
        a7 += __shfl_xor(a7, m, 64);
    }

    __shared__ float lds[THREADS / 64][8];
    const int lane = threadIdx.x & 63;
    const int w    = threadIdx.x >> 6;
    if (lane == 0) {
        lds[w][0] = a0; lds[w][1] = a1; lds[w][2] = a2; lds[w][3] = a3;
        lds[w][4] = a4; lds[w][5] = a5; lds[w][6] = a6; lds[w][7] = a7;
    }
    __syncthreads();
    if (threadIdx.x < 8) {
        const float s = lds[0][threadIdx.x] + lds[1][threadIdx.x]
                      + lds[2][threadIdx.x] + lds[3][threadIdx.x];
        partials[(long)threadIdx.x * NBLK + blk] = s;   // planar by field
    }
}

// Kernel 2: one block, 512 threads = (field f, row b). Each thread sums its
// 32 contiguous partials in double; LDS gather; lanes 0..63 do SI-SDR math.
__global__ __launch_bounds__(512) void pit_finish(
    const float* __restrict__ partials,   // (8, NBLK) planar
    float* __restrict__ out)
{
    const int tid = threadIdx.x;
    const int b   = tid & 63;
    const int f   = tid >> 6;             // 0..7

    // (b,f) partial segment sums are contiguous: partials[f*NBLK + b*NSEG + c]
    const float4* p = reinterpret_cast<const float4*>(partials + (long)f * NBLK + (long)b * NSEG);
    double s = 0.0;
    #pragma unroll
    for (int q = 0; q < NSEG / 4; ++q) {
        const float4 v = p[q];
        s += (double)v.x + (double)v.y + (double)v.z + (double)v.w;
    }

    __shared__ double sums[8][64];
    sums[f][b] = s;
    __syncthreads();

    if (tid >= 64) return;
    const int bb = tid;

    const double p0p0 = sums[0][bb], p1p1 = sums[1][bb];
    const double t1t1 = sums[2][bb], t2t2 = sums[3][bb];
    const double p0t1 = sums[4][bb], p0t2 = sums[5][bb];
    const double p1t1 = sums[6][bb], p1t2 = sums[7][bb];

    const double EPS = 1.1920928955078125e-07; // np.finfo(np.float32).eps

    auto sisdr = [&](double pt, double tt, double pp) -> double {
        const double alpha = (pt + EPS) / (tt + EPS);
        const double ts2   = alpha * alpha * tt;                  // ||alpha*t||^2
        const double n2    = pp - 2.0 * alpha * pt + ts2;         // ||p - alpha*t||^2
        return 10.0 * log10((ts2 + EPS) / (n2 + EPS));
    };

    const double score1 = 0.5 * (sisdr(p0t1, t1t1, p0p0) + sisdr(p1t2, t2t2, p1p1));
    const double score2 = 0.5 * (sisdr(p1t1, t1t1, p1p1) + sisdr(p0t2, t2t2, p0p0));
    double per = fmax(score1, score2);

    #pragma unroll
    for (int m = 32; m >= 1; m >>= 1) per += __shfl_xor(per, m, 64);

    if (bb == 0) out[0] = (float)(-per / (double)Bsz);
}

extern "C" void kernel_launch(void* const* d_in, const int* in_sizes, int n_in,
                              void* d_out, int out_size, void* d_ws, size_t ws_size,
                              hipStream_t stream) {
    const float* preds = (const float*)d_in[0]; // (2, B, L)
    const float* s1    = (const float*)d_in[1]; // (B, L)
    const float* s2    = (const float*)d_in[2]; // (B, L)
    float* out         = (float*)d_out;         // scalar loss
    float* partials    = (float*)d_ws;          // 8*NBLK floats = 64 KB

    pit_dots<<<NBLK, THREADS, 0, stream>>>(preds, s1, s2, partials);
    pit_finish<<<1, 512, 0, stream>>>(partials, out);
}